// Round 2
// baseline (1177.441 us; speedup 1.0000x reference)
//
#include <hip/hip_runtime.h>

// Capsule routing, factorized, all fp32, multi-kernel (NO grid.sync — R1 measured
// ~60us per cooperative grid.sync on MI355X; launch boundaries are cheaper).
// R2: 9 launches (was 12). gemm1 accumulates s via global fp32 atomics (kills the
// 21MB/iter split-K round trip); squash is fused into gemm2's prologue; agreement
// goes through a single atomically-accumulated [1152][10] buffer per iter.
// B=256, K_IN=8, C=1152, J=10, D=16, 4 iters.
// m = k*1152 + c (M=9216), n = j*16 + d (N=160).

#define C_IN  1152
#define J_U   10
#define M_DIM 9216
#define N_DIM 160
#define B_SZ  256

// ---- ws layout (float offsets); ws is 256 MiB so offsets are generous ----
#define OFF_XT   0                    // [9216][256]
#define OFF_WR   2400000              // [9216][160]
#define OFF_S    3900000              // 4 x [256][160]   (atomic s, per iter)
#define OFF_B0   9250000              // [1152][10]
#define OFF_B1   9270000              // [1152][10]
#define OFF_AG   9290000              // 3 x [1152][10]   (atomic agreement, per iter)

// ================= prep: transpose x -> Xt, build Wr, zero atomic buffers ==========
__global__ __launch_bounds__(256) void k_prep(const float* __restrict__ x,
                                              const float* __restrict__ W,
                                              float* __restrict__ ws) {
    const int bid = blockIdx.x, t = threadIdx.x;
    {   // zero the atomic accumulators (4 s buffers + 3 agg buffers)
        const int i = bid * 256 + t;
        if (i < 4 * 40960) (ws + OFF_S)[i] = 0.f;
        if (i < 3 * 11520) (ws + OFF_AG)[i] = 0.f;
    }
    if (bid < 576) {                       // 144 m-tiles x 4 b-tiles, 64x64 transpose
        __shared__ float T[64][65];
        const int m0 = (bid % 144) * 64, b0 = (bid / 144) * 64;
        {
            const int b_l = t >> 2, q = t & 3;
            const float* xp = x + (size_t)(b0 + b_l) * M_DIM + m0 + q * 16;
#pragma unroll
            for (int u = 0; u < 4; ++u) {
                const float4 v = *reinterpret_cast<const float4*>(xp + 4 * u);
                T[q * 16 + 4 * u + 0][b_l] = v.x;
                T[q * 16 + 4 * u + 1][b_l] = v.y;
                T[q * 16 + 4 * u + 2][b_l] = v.z;
                T[q * 16 + 4 * u + 3][b_l] = v.w;
            }
        }
        __syncthreads();
        {
            const int m_l = t >> 2, q = t & 3;
            float* Xt = ws + OFF_XT;
            float4* op = reinterpret_cast<float4*>(Xt + (size_t)(m0 + m_l) * B_SZ + b0 + q * 16);
#pragma unroll
            for (int u = 0; u < 4; ++u)
                op[u] = make_float4(T[m_l][q * 16 + 4 * u], T[m_l][q * 16 + 4 * u + 1],
                                    T[m_l][q * 16 + 4 * u + 2], T[m_l][q * 16 + 4 * u + 3]);
        }
    } else {                               // Wr[(k*C+c)][n] = W[c][n][k]
        const int i = (bid - 576) * 256 + t;    // [0, 368640)
        const int n = i % N_DIM;
        const int c = (i / N_DIM) % C_IN;
        const int kh = i / (N_DIM * C_IN);      // 0..1
        const float4 w = *reinterpret_cast<const float4*>(W + (size_t)c * 1280 + n * 8 + kh * 4);
        float* Wr = ws + OFF_WR;
        const float wv[4] = {w.x, w.y, w.z, w.w};
#pragma unroll
        for (int j = 0; j < 4; ++j)
            Wr[(size_t)((kh * 4 + j) * C_IN + c) * N_DIM + n] = wv[j];
    }
}

// ================= gemm1: 128 chunks(72 m) x 4 b-quarters(64 b) = 512 blocks =======
// Inner loop unchanged (proven). Prologue reads the single atomic agg buffer.
// Epilogue: 40 fp32 atomicAdds per thread into s_out[256][160] (device scope).
__global__ __launch_bounds__(256, 2) void k_gemm1(const float* __restrict__ Xt,
                                                  const float4* __restrict__ Wr4,
                                                  const float* __restrict__ bij_old,
                                                  float* __restrict__ bij_new,
                                                  const float* __restrict__ agg_in,
                                                  float* __restrict__ s_out,
                                                  int first) {
    __shared__ float braw[720];
    __shared__ float csm[720];
    __shared__ float Ws[72 * 160];
    __shared__ alignas(16) float Xs[72 * 64];
    const int ch = blockIdx.x >> 2, bq4 = blockIdx.x & 3;
    const int m0 = ch * 72;
    const int c0 = (ch & 15) * 72;        // chunk sits inside one k-slice (1152/72=16)
    const int t = threadIdx.x;

    if (first) {
        // b_ij == 0: softmax(0) = 1/J exactly.
        for (int idx = t; idx < 720; idx += 256) {
            csm[idx] = 0.1f;
            bij_new[c0 * J_U + idx] = 0.f;
        }
    } else {
        for (int idx = t; idx < 720; idx += 256) {
            const float v = bij_old[c0 * J_U + idx] + agg_in[c0 * J_U + idx];
            braw[idx] = v;
            bij_new[c0 * J_U + idx] = v;
        }
        __syncthreads();
        for (int idx = t; idx < 720; idx += 256) {    // softmax over j
            const int r0 = (idx / J_U) * J_U;
            float mx = -1e30f;
#pragma unroll
            for (int j = 0; j < J_U; ++j) mx = fmaxf(mx, braw[r0 + j]);
            float sum = 0.f;
#pragma unroll
            for (int j = 0; j < J_U; ++j) sum += __expf(braw[r0 + j] - mx);
            csm[idx] = __expf(braw[idx] - mx) / sum;
        }
    }
    __syncthreads();
    // ---- stage scaled W panel + x panel ----
    float4* Ws4 = reinterpret_cast<float4*>(Ws);
    for (int i = t; i < 2880; i += 256) {          // 72 rows x 40 float4
        const int row = i / 40, q = i - row * 40;
        const float sc = csm[row * J_U + (q >> 2)];
        const float4 w = Wr4[(size_t)(m0 + row) * 40 + q];
        Ws4[i] = make_float4(w.x * sc, w.y * sc, w.z * sc, w.w * sc);
    }
    for (int i = t; i < 1152; i += 256) {          // 72 rows x 16 float4 (64 b each)
        const int row = i >> 4, col = i & 15;
        const float4 xv = *reinterpret_cast<const float4*>(
            Xt + (size_t)(m0 + row) * B_SZ + bq4 * 64 + col * 4);
        *reinterpret_cast<float4*>(&Xs[row * 64 + col * 4]) = xv;
    }
    __syncthreads();
    // ---- main loop: pure LDS (x b128 conflict-free, w b64 broadcast) ----
    const int bq = t & 15, ng = t >> 4;
    float acc[4][10] = {};
#pragma unroll 4
    for (int m = 0; m < 72; ++m) {
        const float4 cur = *reinterpret_cast<const float4*>(&Xs[m * 64 + bq * 4]);
        const float2* wr = reinterpret_cast<const float2*>(Ws + m * N_DIM + ng * J_U);
        const float xv[4] = {cur.x, cur.y, cur.z, cur.w};
#pragma unroll
        for (int jj = 0; jj < 5; ++jj) {
            const float2 wv = wr[jj];
#pragma unroll
            for (int i = 0; i < 4; ++i) {
                acc[i][2 * jj]     += xv[i] * wv.x;
                acc[i][2 * jj + 1] += xv[i] * wv.y;
            }
        }
    }
    // ---- atomic split-K accumulation into s[256][160] ----
    float* sd = s_out + (size_t)(bq4 * 64 + bq * 4) * N_DIM + ng * J_U;
#pragma unroll
    for (int i = 0; i < 4; ++i)
#pragma unroll
        for (int q = 0; q < 10; ++q)
            atomicAdd(&sd[(size_t)i * N_DIM + q], acc[i][q]);
}

// ================= gemm2 (+inline squash): 144 m-tiles x 4 b-quarters = 576 blocks ==
// Prologue: read s quarter (L2-hot, 41KB), +1e-5, squash in LDS -> v-panel.
// Main loop + Wr fold unchanged (proven). Epilogue: atomicAdd into agg[1152][10].
__global__ __launch_bounds__(256) void k_gemm2(const float* __restrict__ x,
                                               const float* __restrict__ s_in,
                                               const float* __restrict__ Wr,
                                               float* __restrict__ agg_out) {
    __shared__ alignas(16) float VG[64 * 164];   // v-panel [64][160] then G-tile [64][164]
    __shared__ float agg[640];                   // 64 c x 10 j
    __shared__ float Sc[640];                    // squash scale [64 b][10 j]
    const int mt = blockIdx.x >> 2, bq = blockIdx.x & 3;
    const int m0 = mt * 64, b0 = bq * 64;
    const int t = threadIdx.x;
    const int tm = t & 15, ng = t >> 4;

    // stage s quarter (packed [64][160]) with the reference's pre-magnitude +1e-5
    float4* Vs4 = reinterpret_cast<float4*>(VG);
    const float4* s4 = reinterpret_cast<const float4*>(s_in);
    for (int i = t; i < 2560; i += 256) {
        const float4 sv = s4[(size_t)bq * 2560 + i];
        Vs4[i] = make_float4(sv.x + 1e-5f, sv.y + 1e-5f, sv.z + 1e-5f, sv.w + 1e-5f);
    }
    for (int i = t; i < 640; i += 256) agg[i] = 0.f;
    __syncthreads();
    // squash scales: mag over d=16, scale = sqrt(mag)/(1+mag)
    for (int i2 = t; i2 < 640; i2 += 256) {
        const int r = i2 / J_U, j = i2 - r * J_U;
        float mag = 0.f;
#pragma unroll
        for (int d = 0; d < 16; ++d) {
            const float vv = VG[r * N_DIM + j * 16 + d];
            mag += vv * vv;
        }
        Sc[i2] = sqrtf(mag) / (1.f + mag);
    }
    __syncthreads();
    for (int i2 = t; i2 < 10240; i2 += 256) {    // v = (s+1e-5) * scale, in place
        const int r = i2 / N_DIM, n = i2 - r * N_DIM;
        VG[i2] *= Sc[r * J_U + (n >> 4)];
    }
    __syncthreads();

    // main loop over 64 b: x coalesced (256B/wave-instr), v broadcast from LDS
    float acc[4][10] = {};
    const float* xb = x + (size_t)b0 * M_DIM + m0 + tm * 4;
    const float2* Vs2 = reinterpret_cast<const float2*>(VG);
    float4 pf[4];
#pragma unroll
    for (int i = 0; i < 4; ++i) pf[i] = *reinterpret_cast<const float4*>(xb + (size_t)i * M_DIM);
#pragma unroll 4
    for (int b = 0; b < 64; ++b) {
        const int bf = (b + 4 < 64) ? b + 4 : 63;            // clamped prefetch
        const float4 nxt = *reinterpret_cast<const float4*>(xb + (size_t)bf * M_DIM);
        const float4 cur = pf[0];
        pf[0] = pf[1]; pf[1] = pf[2]; pf[2] = pf[3]; pf[3] = nxt;
        const float2* vv = Vs2 + b * 80 + ng * 5;
        const float xv[4] = {cur.x, cur.y, cur.z, cur.w};
#pragma unroll
        for (int jj = 0; jj < 5; ++jj) {
            const float2 w = vv[jj];
#pragma unroll
            for (int i = 0; i < 4; ++i) {
                acc[i][2 * jj]     += xv[i] * w.x;
                acc[i][2 * jj + 1] += xv[i] * w.y;
            }
        }
    }
    __syncthreads();   // all waves done reading v-panel; reuse VG for G-tile
    // scatter acc -> G-tile (row stride 164 floats = 656 B, 16B-aligned rows)
#pragma unroll
    for (int i = 0; i < 4; ++i)
#pragma unroll
        for (int q = 0; q < 10; ++q)
            VG[(tm * 4 + i) * 164 + ng * 10 + q] = acc[i][q];
    __syncthreads();
    // coalesced fold: 64 rows x 40 float4 of Wr ⊙ G, one j per float4
    const float4* Wr4 = reinterpret_cast<const float4*>(Wr);
    for (int idx = t; idx < 2560; idx += 256) {
        const int row = idx / 40, q = idx - row * 40;
        const float4 w = Wr4[(size_t)(m0 + row) * 40 + q];
        const float4 g = *reinterpret_cast<const float4*>(&VG[row * 164 + q * 4]);
        atomicAdd(&agg[row * J_U + (q >> 2)], w.x * g.x + w.y * g.y + w.z * g.z + w.w * g.w);
    }
    __syncthreads();
    const int k = m0 / C_IN, c02 = m0 - k * C_IN;   // 64-tile never crosses a k-slice
    for (int i = t; i < 640; i += 256)
        atomicAdd(&agg_out[(size_t)c02 * J_U + i], agg[i]);
}

// ================= final squash: s3 -> out (one b per block) =================
__global__ __launch_bounds__(256) void k_out(const float* __restrict__ s_in,
                                             float* __restrict__ out) {
    __shared__ float sq[160];
    const int b = blockIdx.x, t = threadIdx.x;
    float sv = 0.f;
    if (t < 160) {
        sv = s_in[(size_t)b * N_DIM + t] + 1e-5f;
        sq[t] = sv * sv;
    }
    __syncthreads();
    if (t < 160) {
        const int j0 = t & ~15;
        float mag = 0.f;
#pragma unroll
        for (int d = 0; d < 16; ++d) mag += sq[j0 + d];
        out[(size_t)b * N_DIM + t] = sv * (sqrtf(mag) / (1.f + mag));
    }
}

extern "C" void kernel_launch(void* const* d_in, const int* in_sizes, int n_in,
                              void* d_out, int out_size, void* d_ws, size_t ws_size,
                              hipStream_t stream) {
    const float* x = (const float*)d_in[0];   // (256, 8, 1152) fp32
    const float* W = (const float*)d_in[1];   // (1, 1152, 10, 16, 8) fp32
    float* out = (float*)d_out;               // (256, 10, 16, 1) fp32
    float* ws  = (float*)d_ws;
    float* Xt   = ws + OFF_XT;
    float* Wr   = ws + OFF_WR;
    float* bij0 = ws + OFF_B0;
    float* bij1 = ws + OFF_B1;
    const float4* Wr4 = (const float4*)Wr;

    k_prep<<<2016, 256, 0, stream>>>(x, W, ws);

    for (int it = 0; it < 4; ++it) {
        const float* bo = (it & 1) ? bij1 : bij0;
        float*       bn = (it & 1) ? bij0 : bij1;
        float* s_it = ws + OFF_S + it * 40960;
        const float* agg_in = (it == 0) ? bij0 : (ws + OFF_AG + (it - 1) * 11520);
        k_gemm1<<<512, 256, 0, stream>>>(Xt, Wr4, bo, bn, agg_in, s_it, it == 0 ? 1 : 0);
        if (it < 3)
            k_gemm2<<<576, 256, 0, stream>>>(x, s_it, Wr, ws + OFF_AG + it * 11520);
    }
    k_out<<<256, 256, 0, stream>>>(ws + OFF_S + 3 * 40960, out);
}

// Round 3
// 294.810 us; speedup vs baseline: 3.9939x; 3.9939x over previous
//
#include <hip/hip_runtime.h>

// Capsule routing, factorized, all fp32, multi-kernel. Plain stores only —
// R1 (grid.sync ~60us each) and R2 (contended global atomics, 164MB/launch of
// coherence writes) both proved cross-XCD coherence tricks lose to launch
// boundaries on MI355X.
// R3: baseline 12-launch structure, with b-widened inner loops to cut the
// LDS-issue bottleneck (w-broadcast reads amortized over 8 b per thread).
// B=256, K_IN=8, C=1152, J=10, D=16, 4 iters.
// m = k*1152 + c (M=9216), n = j*16 + d (N=160).

#define C_IN  1152
#define J_U   10
#define M_DIM 9216
#define N_DIM 160
#define B_SZ  256

// ---- ws layout (float offsets); ws is 256 MiB so offsets are generous ----
#define OFF_XT   0                    // [9216][256]
#define OFF_WR   2400000              // [9216][160]
#define OFF_SP   3900000              // [128][256][160]
#define OFF_V    9200000              // [256][160]
#define OFF_B0   9250000              // [1152][10]
#define OFF_B1   9270000              // [1152][10]
#define OFF_AG   9290000              // [32][1152][10]

// ================= prep: transpose x -> Xt, build Wr (unchanged, proven) ==========
__global__ __launch_bounds__(256) void k_prep(const float* __restrict__ x,
                                              const float* __restrict__ W,
                                              float* __restrict__ ws) {
    const int bid = blockIdx.x, t = threadIdx.x;
    if (bid < 576) {                       // 144 m-tiles x 4 b-tiles, 64x64 transpose
        __shared__ float T[64][65];
        const int m0 = (bid % 144) * 64, b0 = (bid / 144) * 64;
        {
            const int b_l = t >> 2, q = t & 3;
            const float* xp = x + (size_t)(b0 + b_l) * M_DIM + m0 + q * 16;
#pragma unroll
            for (int u = 0; u < 4; ++u) {
                const float4 v = *reinterpret_cast<const float4*>(xp + 4 * u);
                T[q * 16 + 4 * u + 0][b_l] = v.x;
                T[q * 16 + 4 * u + 1][b_l] = v.y;
                T[q * 16 + 4 * u + 2][b_l] = v.z;
                T[q * 16 + 4 * u + 3][b_l] = v.w;
            }
        }
        __syncthreads();
        {
            const int m_l = t >> 2, q = t & 3;
            float* Xt = ws + OFF_XT;
            float4* op = reinterpret_cast<float4*>(Xt + (size_t)(m0 + m_l) * B_SZ + b0 + q * 16);
#pragma unroll
            for (int u = 0; u < 4; ++u)
                op[u] = make_float4(T[m_l][q * 16 + 4 * u], T[m_l][q * 16 + 4 * u + 1],
                                    T[m_l][q * 16 + 4 * u + 2], T[m_l][q * 16 + 4 * u + 3]);
        }
    } else {                               // Wr[(k*C+c)][n] = W[c][n][k]
        const int i = (bid - 576) * 256 + t;    // [0, 368640)
        const int n = i % N_DIM;
        const int c = (i / N_DIM) % C_IN;
        const int kh = i / (N_DIM * C_IN);      // 0..1
        const float4 w = *reinterpret_cast<const float4*>(W + (size_t)c * 1280 + n * 8 + kh * 4);
        float* Wr = ws + OFF_WR;
        const float wv[4] = {w.x, w.y, w.z, w.w};
#pragma unroll
        for (int j = 0; j < 4; ++j)
            Wr[(size_t)((kh * 4 + j) * C_IN + c) * N_DIM + n] = wv[j];
    }
}

// ================= gemm1: 128 chunks(72 m) x 2 b-halves(128 b) = 256 blocks =======
// Each thread: 8 b x 10 n (w-broadcast amortized 2x vs baseline: 7 LDS instrs per
// 80 FMAs). Xs split into two 64-wide sub-panels so both b128 x-reads keep the
// free 2-way bank profile (a flat [m][128] layout would be 4-way conflicted).
__global__ __launch_bounds__(256, 1) void k_gemm1(const float* __restrict__ Xt,
                                                  const float4* __restrict__ Wr4,
                                                  const float* __restrict__ bij_old,
                                                  float* __restrict__ bij_new,
                                                  const float* __restrict__ agg_part,
                                                  float* __restrict__ s_part,
                                                  int first) {
    __shared__ float braw[720];
    __shared__ float csm[720];
    __shared__ float Ws[72 * 160];
    __shared__ alignas(16) float Xs[2 * 72 * 64];   // [half][m][64]
    const int ch = blockIdx.x >> 1, bh = blockIdx.x & 1;
    const int m0 = ch * 72;
    const int c0 = (ch & 15) * 72;        // chunk sits inside one k-slice (1152/72=16)
    const int t = threadIdx.x;

    if (first) {
        // b_ij == 0: softmax(0) = 1/J exactly; skip the 32-slice agg read.
        for (int idx = t; idx < 720; idx += 256) {
            csm[idx] = 0.1f;
            bij_new[c0 * J_U + idx] = 0.f;
        }
    } else {
        for (int idx = t; idx < 720; idx += 256) {
            float v = bij_old[c0 * J_U + idx];
#pragma unroll
            for (int s = 0; s < 32; ++s) v += agg_part[s * 11520 + c0 * J_U + idx];
            braw[idx] = v;
            bij_new[c0 * J_U + idx] = v;    // both bh-blocks write identical values
        }
        __syncthreads();
        for (int idx = t; idx < 720; idx += 256) {    // softmax over j
            const int r0 = (idx / J_U) * J_U;
            float mx = -1e30f;
#pragma unroll
            for (int j = 0; j < J_U; ++j) mx = fmaxf(mx, braw[r0 + j]);
            float sum = 0.f;
#pragma unroll
            for (int j = 0; j < J_U; ++j) sum += __expf(braw[r0 + j] - mx);
            csm[idx] = __expf(braw[idx] - mx) / sum;
        }
    }
    __syncthreads();
    // ---- stage scaled W panel + split x panel ----
    float4* Ws4 = reinterpret_cast<float4*>(Ws);
    for (int i = t; i < 2880; i += 256) {          // 72 rows x 40 float4
        const int row = i / 40, q = i - row * 40;
        const float sc = csm[row * J_U + (q >> 2)];
        const float4 w = Wr4[(size_t)(m0 + row) * 40 + q];
        Ws4[i] = make_float4(w.x * sc, w.y * sc, w.z * sc, w.w * sc);
    }
    for (int i = t; i < 2304; i += 256) {          // 72 rows x 32 float4 (128 b)
        const int row = i >> 5, col = i & 31;      // col = 2*bq + half
        const float4 xv = *reinterpret_cast<const float4*>(
            Xt + (size_t)(m0 + row) * B_SZ + bh * 128 + col * 4);
        *reinterpret_cast<float4*>(&Xs[(col & 1) * 4608 + row * 64 + (col >> 1) * 4]) = xv;
    }
    __syncthreads();
    // ---- main loop: 2x b128 (x, 2-way free) + 5x b64 (w broadcast) per 80 FMA ----
    const int bq = t & 15, ng = t >> 4;
    float acc[8][10] = {};
#pragma unroll 2
    for (int m = 0; m < 72; ++m) {
        const float4 x0 = *reinterpret_cast<const float4*>(&Xs[m * 64 + bq * 4]);
        const float4 x1 = *reinterpret_cast<const float4*>(&Xs[4608 + m * 64 + bq * 4]);
        const float2* wr = reinterpret_cast<const float2*>(Ws + m * N_DIM + ng * J_U);
        const float xv[8] = {x0.x, x0.y, x0.z, x0.w, x1.x, x1.y, x1.z, x1.w};
#pragma unroll
        for (int jj = 0; jj < 5; ++jj) {
            const float2 wv = wr[jj];
#pragma unroll
            for (int i = 0; i < 8; ++i) {
                acc[i][2 * jj]     += xv[i] * wv.x;
                acc[i][2 * jj + 1] += xv[i] * wv.y;
            }
        }
    }
    // ---- store split-K partials (plain stores, layout identical to baseline) ----
    // thread's b: bh*128 + bq*8 + i, with i<4 from x0-panel, i>=4 from x1-panel
    float* sp = s_part + (size_t)ch * 40960 + (size_t)(bh * 128 + bq * 8) * N_DIM + ng * J_U;
#pragma unroll
    for (int i = 0; i < 8; ++i) {
        const int b_off = (i < 4) ? i : (i - 4 + 4);   // i maps directly: x0->b+0..3, x1->b+4..7
        float2* p = reinterpret_cast<float2*>(sp + (size_t)b_off * N_DIM);
#pragma unroll
        for (int jj = 0; jj < 5; ++jj) p[jj] = make_float2(acc[i][2 * jj], acc[i][2 * jj + 1]);
    }
}

// ================= squash: reduce 128 slices (4-way h-split), squash -> dst ========
__global__ __launch_bounds__(640) void k_squash(const float* __restrict__ s_part,
                                                float* __restrict__ dst) {
    __shared__ float red[640];
    __shared__ float sq[160];
    const int b = blockIdx.x, t = threadIdx.x;
    const int n = t % 160, h = t / 160;            // h in 0..3, 32 slices each
    float s = 0.f;
    const float* p = s_part + (size_t)h * 32 * 40960 + (size_t)b * N_DIM + n;
#pragma unroll 8
    for (int sl = 0; sl < 32; ++sl) s += p[(size_t)sl * 40960];
    red[t] = s;
    __syncthreads();
    if (t < 160) {
        s = red[t] + red[t + 160] + red[t + 320] + red[t + 480] + 1e-5f;  // +1e-5 BEFORE mags
        sq[t] = s * s;
        red[t] = s;
    }
    __syncthreads();
    if (t < 160) {
        const int j0 = t & ~15;
        float mag = 0.f;
#pragma unroll
        for (int d = 0; d < 16; ++d) mag += sq[j0 + d];
        dst[(size_t)b * N_DIM + t] = red[t] * (sqrtf(mag) / (1.f + mag));
    }
}

// ================= gemm2: 144 m-tiles(64) x 4 b-quarters(64 b), 128 threads =========
// Each thread: 8 m x 10 n -> 2 global b128 (x) + 5 LDS b64 (v broadcast) per 80 FMA.
// 44.5KB LDS -> 3 blocks/CU. Fold path identical to baseline.
__global__ __launch_bounds__(128, 1) void k_gemm2(const float* __restrict__ x,
                                                  const float* __restrict__ v,
                                                  const float* __restrict__ Wr,
                                                  float* __restrict__ agg_part) {
    __shared__ alignas(16) float VG[64 * 164];   // v-panel [64][160] then G-tile [64][164]
    __shared__ float agg[640];                   // 64 c x 10 j
    const int mt = blockIdx.x >> 2, bq = blockIdx.x & 3;
    const int m0 = mt * 64, b0 = bq * 64;
    const int t = threadIdx.x;
    const int tm = t & 7, ng = t >> 3;

    // stage v quarter (packed [64][160])
    float4* Vs4 = reinterpret_cast<float4*>(VG);
    const float4* v4 = reinterpret_cast<const float4*>(v);
    for (int i = t; i < 2560; i += 128) Vs4[i] = v4[(size_t)bq * 2560 + i];
    for (int i = t; i < 640; i += 128) agg[i] = 0.f;
    __syncthreads();

    // main loop over 64 b: x coalesced (8 floats/lane), v broadcast from LDS
    float acc[8][10] = {};
    const float* xb = x + (size_t)b0 * M_DIM + m0 + tm * 8;
    const float2* Vs2 = reinterpret_cast<const float2*>(VG);
    float4 pf0[4], pf1[4];
#pragma unroll
    for (int i = 0; i < 4; ++i) {
        pf0[i] = *reinterpret_cast<const float4*>(xb + (size_t)i * M_DIM);
        pf1[i] = *reinterpret_cast<const float4*>(xb + (size_t)i * M_DIM + 4);
    }
#pragma unroll 4
    for (int b = 0; b < 64; ++b) {
        const int bf = (b + 4 < 64) ? b + 4 : 63;            // clamped prefetch
        const float4 n0 = *reinterpret_cast<const float4*>(xb + (size_t)bf * M_DIM);
        const float4 n1 = *reinterpret_cast<const float4*>(xb + (size_t)bf * M_DIM + 4);
        const float4 c0 = pf0[0], c1 = pf1[0];
        pf0[0] = pf0[1]; pf0[1] = pf0[2]; pf0[2] = pf0[3]; pf0[3] = n0;
        pf1[0] = pf1[1]; pf1[1] = pf1[2]; pf1[2] = pf1[3]; pf1[3] = n1;
        const float2* vvp = Vs2 + b * 80 + ng * 5;
        const float xv[8] = {c0.x, c0.y, c0.z, c0.w, c1.x, c1.y, c1.z, c1.w};
#pragma unroll
        for (int jj = 0; jj < 5; ++jj) {
            const float2 w = vvp[jj];
#pragma unroll
            for (int i = 0; i < 8; ++i) {
                acc[i][2 * jj]     += xv[i] * w.x;
                acc[i][2 * jj + 1] += xv[i] * w.y;
            }
        }
    }
    __syncthreads();   // all waves done reading v-panel; reuse VG for G-tile
    // scatter acc -> G-tile (rows tm*8..tm*8+7)
#pragma unroll
    for (int i = 0; i < 8; ++i)
#pragma unroll
        for (int q = 0; q < 10; ++q)
            VG[(tm * 8 + i) * 164 + ng * J_U + q] = acc[i][q];
    __syncthreads();
    // coalesced fold: 64 rows x 40 float4 of Wr ⊙ G, one j per float4
    const float4* Wr4 = reinterpret_cast<const float4*>(Wr);
    for (int idx = t; idx < 2560; idx += 128) {
        const int row = idx / 40, q = idx - row * 40;
        const float4 w = Wr4[(size_t)(m0 + row) * 40 + q];
        const float4 g = *reinterpret_cast<const float4*>(&VG[row * 164 + q * 4]);
        atomicAdd(&agg[row * J_U + (q >> 2)], w.x * g.x + w.y * g.y + w.z * g.z + w.w * g.w);
    }
    __syncthreads();
    const int k = m0 / C_IN, c02 = m0 - k * C_IN;   // 64-tile never crosses a k-slice
    for (int i = t; i < 640; i += 128)
        agg_part[(size_t)(bq * 8 + k) * 11520 + c02 * J_U + i] = agg[i];
}

extern "C" void kernel_launch(void* const* d_in, const int* in_sizes, int n_in,
                              void* d_out, int out_size, void* d_ws, size_t ws_size,
                              hipStream_t stream) {
    const float* x = (const float*)d_in[0];   // (256, 8, 1152) fp32
    const float* W = (const float*)d_in[1];   // (1, 1152, 10, 16, 8) fp32
    float* out = (float*)d_out;               // (256, 10, 16, 1) fp32
    float* ws  = (float*)d_ws;
    float* Xt   = ws + OFF_XT;
    float* Wr   = ws + OFF_WR;
    float* sp   = ws + OFF_SP;
    float* v    = ws + OFF_V;
    float* bij0 = ws + OFF_B0;
    float* bij1 = ws + OFF_B1;
    float* agg  = ws + OFF_AG;
    const float4* Wr4 = (const float4*)Wr;

    k_prep<<<2016, 256, 0, stream>>>(x, W, ws);

    for (int it = 0; it < 4; ++it) {
        const float* bo = (it & 1) ? bij1 : bij0;
        float*       bn = (it & 1) ? bij0 : bij1;
        k_gemm1<<<256, 256, 0, stream>>>(Xt, Wr4, bo, bn, agg, sp, it == 0 ? 1 : 0);
        k_squash<<<256, 640, 0, stream>>>(sp, (it < 3) ? v : out);
        if (it < 3)   // last iteration's agreement is never used
            k_gemm2<<<576, 128, 0, stream>>>(x, v, Wr, agg);
    }
}

// Round 4
// 289.385 us; speedup vs baseline: 4.0688x; 1.0187x over previous
//
#include <hip/hip_runtime.h>

// Capsule routing, factorized, all fp32, multi-kernel, plain stores only.
// R1: grid.sync ~60us each on MI355X -> never cooperative. R2: contended global
// atomics serialize at coherence point (164MB/launch) -> never atomics.
// R3: dropping to 4 waves/CU regressed -> kernels are LATENCY-bound, not
// LDS-throughput-bound. R4: gemm1 chunk 36m -> 38KB LDS -> 4 blocks/CU
// (16 waves/CU, 2x baseline). gemm2/prep byte-identical to proven round-0.
// B=256, K_IN=8, C=1152, J=10, D=16, 4 iters.
// m = k*1152 + c (M=9216), n = j*16 + d (N=160).

#define C_IN  1152
#define J_U   10
#define M_DIM 9216
#define N_DIM 160
#define B_SZ  256

// ---- ws layout (float offsets); ws is 256 MiB (64M floats) ----
#define OFF_XT   0                    // [9216][256]
#define OFF_WR   2400000              // [9216][160]
#define OFF_SP   3900000              // [256][256][160] = 10.49M floats
#define OFF_V    14500000             // [256][160]
#define OFF_B0   14600000             // [1152][10]
#define OFF_B1   14620000             // [1152][10]
#define OFF_AG   14640000             // [32][1152][10]

// ================= prep: transpose x -> Xt, build Wr (round-0 proven) ==========
__global__ __launch_bounds__(256) void k_prep(const float* __restrict__ x,
                                              const float* __restrict__ W,
                                              float* __restrict__ ws) {
    const int bid = blockIdx.x, t = threadIdx.x;
    if (bid < 576) {                       // 144 m-tiles x 4 b-tiles, 64x64 transpose
        __shared__ float T[64][65];
        const int m0 = (bid % 144) * 64, b0 = (bid / 144) * 64;
        {
            const int b_l = t >> 2, q = t & 3;
            const float* xp = x + (size_t)(b0 + b_l) * M_DIM + m0 + q * 16;
#pragma unroll
            for (int u = 0; u < 4; ++u) {
                const float4 v = *reinterpret_cast<const float4*>(xp + 4 * u);
                T[q * 16 + 4 * u + 0][b_l] = v.x;
                T[q * 16 + 4 * u + 1][b_l] = v.y;
                T[q * 16 + 4 * u + 2][b_l] = v.z;
                T[q * 16 + 4 * u + 3][b_l] = v.w;
            }
        }
        __syncthreads();
        {
            const int m_l = t >> 2, q = t & 3;
            float* Xt = ws + OFF_XT;
            float4* op = reinterpret_cast<float4*>(Xt + (size_t)(m0 + m_l) * B_SZ + b0 + q * 16);
#pragma unroll
            for (int u = 0; u < 4; ++u)
                op[u] = make_float4(T[m_l][q * 16 + 4 * u], T[m_l][q * 16 + 4 * u + 1],
                                    T[m_l][q * 16 + 4 * u + 2], T[m_l][q * 16 + 4 * u + 3]);
        }
    } else {                               // Wr[(k*C+c)][n] = W[c][n][k]
        const int i = (bid - 576) * 256 + t;    // [0, 368640)
        const int n = i % N_DIM;
        const int c = (i / N_DIM) % C_IN;
        const int kh = i / (N_DIM * C_IN);      // 0..1
        const float4 w = *reinterpret_cast<const float4*>(W + (size_t)c * 1280 + n * 8 + kh * 4);
        float* Wr = ws + OFF_WR;
        const float wv[4] = {w.x, w.y, w.z, w.w};
#pragma unroll
        for (int j = 0; j < 4; ++j)
            Wr[(size_t)((kh * 4 + j) * C_IN + c) * N_DIM + n] = wv[j];
    }
}

// ================= gemm1: 256 chunks(36 m) x 4 b-quarters(64 b) = 1024 blocks ======
// LDS 38KB -> 4 blocks/CU = 16 waves/CU (2x round-0) for latency hiding.
// Inner loop structure identical to proven round-0 (1x b128 + 5x b64 per 40 FMA).
__global__ __launch_bounds__(256, 4) void k_gemm1(const float* __restrict__ Xt,
                                                  const float4* __restrict__ Wr4,
                                                  const float* __restrict__ bij_old,
                                                  float* __restrict__ bij_new,
                                                  const float* __restrict__ agg_part,
                                                  float* __restrict__ s_part,
                                                  int first) {
    __shared__ float braw[720];
    __shared__ float csm[720];
    __shared__ float Ws[36 * 160];
    __shared__ alignas(16) float Xs[36 * 64];
    const int ch = blockIdx.x >> 2, bq4 = blockIdx.x & 3;
    const int m0 = ch * 36;
    const int c0 = (ch & 31) * 36;        // chunk sits inside one k-slice (1152/36=32)
    const int t = threadIdx.x;

    if (first) {
        // b_ij == 0: softmax(0) = 1/J exactly; skip the 32-slice agg read.
        for (int idx = t; idx < 720; idx += 256) {
            csm[idx] = 0.1f;
            bij_new[c0 * J_U + idx] = 0.f;
        }
    } else {
        for (int idx = t; idx < 720; idx += 256) {
            float v = bij_old[c0 * J_U + idx];
#pragma unroll
            for (int s = 0; s < 32; ++s) v += agg_part[s * 11520 + c0 * J_U + idx];
            braw[idx] = v;
            bij_new[c0 * J_U + idx] = v;   // bq-duplicate writes are identical values
        }
        __syncthreads();
        for (int idx = t; idx < 720; idx += 256) {    // softmax over j
            const int r0 = (idx / J_U) * J_U;
            float mx = -1e30f;
#pragma unroll
            for (int j = 0; j < J_U; ++j) mx = fmaxf(mx, braw[r0 + j]);
            float sum = 0.f;
#pragma unroll
            for (int j = 0; j < J_U; ++j) sum += __expf(braw[r0 + j] - mx);
            csm[idx] = __expf(braw[idx] - mx) / sum;
        }
    }
    __syncthreads();
    // ---- stage scaled W panel + x panel ----
    float4* Ws4 = reinterpret_cast<float4*>(Ws);
    for (int i = t; i < 1440; i += 256) {          // 36 rows x 40 float4
        const int row = i / 40, q = i - row * 40;
        const float sc = csm[row * J_U + (q >> 2)];
        const float4 w = Wr4[(size_t)(m0 + row) * 40 + q];
        Ws4[i] = make_float4(w.x * sc, w.y * sc, w.z * sc, w.w * sc);
    }
    for (int i = t; i < 576; i += 256) {           // 36 rows x 16 float4 (64 b each)
        const int row = i >> 4, col = i & 15;
        const float4 xv = *reinterpret_cast<const float4*>(
            Xt + (size_t)(m0 + row) * B_SZ + bq4 * 64 + col * 4);
        *reinterpret_cast<float4*>(&Xs[row * 64 + col * 4]) = xv;
    }
    __syncthreads();
    // ---- main loop: pure LDS (x b128 conflict-free, w b64 broadcast) ----
    const int bq = t & 15, ng = t >> 4;
    float acc[4][10] = {};
#pragma unroll 4
    for (int m = 0; m < 36; ++m) {
        const float4 cur = *reinterpret_cast<const float4*>(&Xs[m * 64 + bq * 4]);
        const float2* wr = reinterpret_cast<const float2*>(Ws + m * N_DIM + ng * J_U);
        const float xv[4] = {cur.x, cur.y, cur.z, cur.w};
#pragma unroll
        for (int jj = 0; jj < 5; ++jj) {
            const float2 wv = wr[jj];
#pragma unroll
            for (int i = 0; i < 4; ++i) {
                acc[i][2 * jj]     += xv[i] * wv.x;
                acc[i][2 * jj + 1] += xv[i] * wv.y;
            }
        }
    }
    // ---- store split-K partials (plain stores) ----
    float* sp = s_part + (size_t)ch * 40960 + (size_t)(bq4 * 64 + bq * 4) * N_DIM + ng * J_U;
#pragma unroll
    for (int i = 0; i < 4; ++i) {
        float2* p = reinterpret_cast<float2*>(sp + (size_t)i * N_DIM);
#pragma unroll
        for (int jj = 0; jj < 5; ++jj) p[jj] = make_float2(acc[i][2 * jj], acc[i][2 * jj + 1]);
    }
}

// ================= squash: reduce 256 slices (4-way h-split), squash -> dst ========
__global__ __launch_bounds__(640) void k_squash(const float* __restrict__ s_part,
                                                float* __restrict__ dst) {
    __shared__ float red[640];
    __shared__ float sq[160];
    const int b = blockIdx.x, t = threadIdx.x;
    const int n = t % 160, h = t / 160;            // h in 0..3, 64 slices each
    float s = 0.f;
    const float* p = s_part + (size_t)h * 64 * 40960 + (size_t)b * N_DIM + n;
#pragma unroll 8
    for (int sl = 0; sl < 64; ++sl) s += p[(size_t)sl * 40960];
    red[t] = s;
    __syncthreads();
    if (t < 160) {
        s = red[t] + red[t + 160] + red[t + 320] + red[t + 480] + 1e-5f;  // +1e-5 BEFORE mags
        sq[t] = s * s;
        red[t] = s;
    }
    __syncthreads();
    if (t < 160) {
        const int j0 = t & ~15;
        float mag = 0.f;
#pragma unroll
        for (int d = 0; d < 16; ++d) mag += sq[j0 + d];
        dst[(size_t)b * N_DIM + t] = red[t] * (sqrtf(mag) / (1.f + mag));
    }
}

// ================= gemm2: round-0 proven version, unchanged =========
__global__ __launch_bounds__(256) void k_gemm2(const float* __restrict__ x,
                                               const float* __restrict__ v,
                                               const float* __restrict__ Wr,
                                               float* __restrict__ agg_part) {
    __shared__ alignas(16) float VG[64 * 164];   // v-panel [64][160] then G-tile [64][164]
    __shared__ float agg[640];                   // 64 c x 10 j
    const int mt = blockIdx.x >> 2, bq = blockIdx.x & 3;
    const int m0 = mt * 64, b0 = bq * 64;
    const int t = threadIdx.x;
    const int tm = t & 15, ng = t >> 4;

    // stage v quarter (packed [64][160])
    float4* Vs4 = reinterpret_cast<float4*>(VG);
    const float4* v4 = reinterpret_cast<const float4*>(v);
    for (int i = t; i < 2560; i += 256) Vs4[i] = v4[(size_t)bq * 2560 + i];
    for (int i = t; i < 640; i += 256) agg[i] = 0.f;
    __syncthreads();

    // main loop over 64 b: x coalesced (256B/wave-instr), v broadcast from LDS
    float acc[4][10] = {};
    const float* xb = x + (size_t)b0 * M_DIM + m0 + tm * 4;
    const float2* Vs2 = reinterpret_cast<const float2*>(VG);
    float4 pf[4];
#pragma unroll
    for (int i = 0; i < 4; ++i) pf[i] = *reinterpret_cast<const float4*>(xb + (size_t)i * M_DIM);
#pragma unroll 4
    for (int b = 0; b < 64; ++b) {
        const int bf = (b + 4 < 64) ? b + 4 : 63;            // clamped prefetch
        const float4 nxt = *reinterpret_cast<const float4*>(xb + (size_t)bf * M_DIM);
        const float4 cur = pf[0];
        pf[0] = pf[1]; pf[1] = pf[2]; pf[2] = pf[3]; pf[3] = nxt;
        const float2* vv = Vs2 + b * 80 + ng * 5;
        const float xv[4] = {cur.x, cur.y, cur.z, cur.w};
#pragma unroll
        for (int jj = 0; jj < 5; ++jj) {
            const float2 w = vv[jj];
#pragma unroll
            for (int i = 0; i < 4; ++i) {
                acc[i][2 * jj]     += xv[i] * w.x;
                acc[i][2 * jj + 1] += xv[i] * w.y;
            }
        }
    }
    __syncthreads();   // all waves done reading v-panel; reuse VG for G-tile
    // scatter acc -> G-tile (row stride 164 floats = 656 B, 16B-aligned rows)
#pragma unroll
    for (int i = 0; i < 4; ++i)
#pragma unroll
        for (int q = 0; q < 10; ++q)
            VG[(tm * 4 + i) * 164 + ng * 10 + q] = acc[i][q];
    __syncthreads();
    // coalesced fold: 64 rows x 40 float4 of Wr ⊙ G, one j per float4
    const float4* Wr4 = reinterpret_cast<const float4*>(Wr);
    for (int idx = t; idx < 2560; idx += 256) {
        const int row = idx / 40, q = idx - row * 40;
        const float4 w = Wr4[(size_t)(m0 + row) * 40 + q];
        const float4 g = *reinterpret_cast<const float4*>(&VG[row * 164 + q * 4]);
        atomicAdd(&agg[row * J_U + (q >> 2)], w.x * g.x + w.y * g.y + w.z * g.z + w.w * g.w);
    }
    __syncthreads();
    const int k = m0 / C_IN, c0 = m0 - k * C_IN;   // 64-tile never crosses a k-slice
    for (int i = t; i < 640; i += 256)
        agg_part[(size_t)(bq * 8 + k) * 11520 + c0 * J_U + i] = agg[i];
}

extern "C" void kernel_launch(void* const* d_in, const int* in_sizes, int n_in,
                              void* d_out, int out_size, void* d_ws, size_t ws_size,
                              hipStream_t stream) {
    const float* x = (const float*)d_in[0];   // (256, 8, 1152) fp32
    const float* W = (const float*)d_in[1];   // (1, 1152, 10, 16, 8) fp32
    float* out = (float*)d_out;               // (256, 10, 16, 1) fp32
    float* ws  = (float*)d_ws;
    float* Xt   = ws + OFF_XT;
    float* Wr   = ws + OFF_WR;
    float* sp   = ws + OFF_SP;
    float* v    = ws + OFF_V;
    float* bij0 = ws + OFF_B0;
    float* bij1 = ws + OFF_B1;
    float* agg  = ws + OFF_AG;
    const float4* Wr4 = (const float4*)Wr;

    k_prep<<<2016, 256, 0, stream>>>(x, W, ws);

    for (int it = 0; it < 4; ++it) {
        const float* bo = (it & 1) ? bij1 : bij0;
        float*       bn = (it & 1) ? bij0 : bij1;
        k_gemm1<<<1024, 256, 0, stream>>>(Xt, Wr4, bo, bn, agg, sp, it == 0 ? 1 : 0);
        k_squash<<<256, 640, 0, stream>>>(sp, (it < 3) ? v : out);
        if (it < 3)   // last iteration's agreement is never used
            k_gemm2<<<576, 256, 0, stream>>>(x, v, Wr, agg);
    }
}

// Round 5
// 264.726 us; speedup vs baseline: 4.4478x; 1.0932x over previous
//
#include <hip/hip_runtime.h>

// Capsule routing, factorized, all fp32, multi-kernel, plain stores only.
// Session ledger: R1 coop grid.sync ~60us each -> never. R2 contended global
// atomics -> 164MB/launch coherence writes -> never. R3 4 waves/CU (wide
// per-thread tiles) = 294.8us. R4 16 waves/CU (256 split-K slices) = 289.4us.
// R0 baseline (8 waves/CU, 128 slices) = 271.3us = best -> this round keeps R0
// byte-identical except: (a) XCD-aware swizzle in gemm1/gemm2 so the 4
// bq-siblings of a ch/mt share an XCD L2 (Wr panel + agg slices fetched once
// per XCD instead of 4x), (b) squash widened to 640 threads (4-way h-split).
// B=256, K_IN=8, C=1152, J=10, D=16, 4 iters.
// m = k*1152 + c (M=9216), n = j*16 + d (N=160).

#define C_IN  1152
#define J_U   10
#define M_DIM 9216
#define N_DIM 160
#define B_SZ  256

// ---- ws layout (float offsets); ws is 256 MiB so offsets are generous ----
#define OFF_XT   0                    // [9216][256]
#define OFF_WR   2400000              // [9216][160]
#define OFF_SP   3900000              // [128][256][160]
#define OFF_V    9200000              // [256][160]
#define OFF_B0   9250000              // [1152][10]
#define OFF_B1   9270000              // [1152][10]
#define OFF_AG   9290000              // [32][1152][10]

// ================= prep: transpose x -> Xt, build Wr =================
__global__ __launch_bounds__(256) void k_prep(const float* __restrict__ x,
                                              const float* __restrict__ W,
                                              float* __restrict__ ws) {
    const int bid = blockIdx.x, t = threadIdx.x;
    if (bid < 576) {                       // 144 m-tiles x 4 b-tiles, 64x64 transpose
        __shared__ float T[64][65];
        const int m0 = (bid % 144) * 64, b0 = (bid / 144) * 64;
        {
            const int b_l = t >> 2, q = t & 3;
            const float* xp = x + (size_t)(b0 + b_l) * M_DIM + m0 + q * 16;
#pragma unroll
            for (int u = 0; u < 4; ++u) {
                const float4 v = *reinterpret_cast<const float4*>(xp + 4 * u);
                T[q * 16 + 4 * u + 0][b_l] = v.x;
                T[q * 16 + 4 * u + 1][b_l] = v.y;
                T[q * 16 + 4 * u + 2][b_l] = v.z;
                T[q * 16 + 4 * u + 3][b_l] = v.w;
            }
        }
        __syncthreads();
        {
            const int m_l = t >> 2, q = t & 3;
            float* Xt = ws + OFF_XT;
            float4* op = reinterpret_cast<float4*>(Xt + (size_t)(m0 + m_l) * B_SZ + b0 + q * 16);
#pragma unroll
            for (int u = 0; u < 4; ++u)
                op[u] = make_float4(T[m_l][q * 16 + 4 * u], T[m_l][q * 16 + 4 * u + 1],
                                    T[m_l][q * 16 + 4 * u + 2], T[m_l][q * 16 + 4 * u + 3]);
        }
    } else {                               // Wr[(k*C+c)][n] = W[c][n][k]
        const int i = (bid - 576) * 256 + t;    // [0, 368640)
        const int n = i % N_DIM;
        const int c = (i / N_DIM) % C_IN;
        const int kh = i / (N_DIM * C_IN);      // 0..1
        const float4 w = *reinterpret_cast<const float4*>(W + (size_t)c * 1280 + n * 8 + kh * 4);
        float* Wr = ws + OFF_WR;
        const float wv[4] = {w.x, w.y, w.z, w.w};
#pragma unroll
        for (int j = 0; j < 4; ++j)
            Wr[(size_t)((kh * 4 + j) * C_IN + c) * N_DIM + n] = wv[j];
    }
}

// ================= gemm1: 128 chunks(72 m) x 4 b-quarters(64 b) = 512 blocks =======
// XCD swizzle: vb = (bid%8)*64 + bid/8 (bijective, 512 = 8x64). The 4 bq-siblings
// of a ch land on one XCD -> Wr panel + agg slices hit that XCD's L2 once.
__global__ __launch_bounds__(256, 2) void k_gemm1(const float* __restrict__ Xt,
                                                  const float4* __restrict__ Wr4,
                                                  const float* __restrict__ bij_old,
                                                  float* __restrict__ bij_new,
                                                  const float* __restrict__ agg_part,
                                                  float* __restrict__ s_part,
                                                  int first) {
    __shared__ float braw[720];
    __shared__ float csm[720];
    __shared__ float Ws[72 * 160];
    __shared__ alignas(16) float Xs[72 * 64];
    const int vb = (blockIdx.x & 7) * 64 + (blockIdx.x >> 3);   // XCD-aware remap
    const int ch = vb >> 2, bq4 = vb & 3;
    const int m0 = ch * 72;
    const int c0 = (ch & 15) * 72;        // chunk sits inside one k-slice (1152/72=16)
    const int t = threadIdx.x;

    if (first) {
        // b_ij == 0: softmax(0) = 1/J exactly; skip the 32-slice agg read.
        for (int idx = t; idx < 720; idx += 256) {
            csm[idx] = 0.1f;
            bij_new[c0 * J_U + idx] = 0.f;
        }
    } else {
        for (int idx = t; idx < 720; idx += 256) {
            float v = bij_old[c0 * J_U + idx];
#pragma unroll
            for (int s = 0; s < 32; ++s) v += agg_part[s * 11520 + c0 * J_U + idx];
            braw[idx] = v;
            bij_new[c0 * J_U + idx] = v;   // bq-duplicate writes are identical values
        }
        __syncthreads();
        for (int idx = t; idx < 720; idx += 256) {    // softmax over j
            const int r0 = (idx / J_U) * J_U;
            float mx = -1e30f;
#pragma unroll
            for (int j = 0; j < J_U; ++j) mx = fmaxf(mx, braw[r0 + j]);
            float sum = 0.f;
#pragma unroll
            for (int j = 0; j < J_U; ++j) sum += __expf(braw[r0 + j] - mx);
            csm[idx] = __expf(braw[idx] - mx) / sum;
        }
    }
    __syncthreads();
    // ---- stage scaled W panel + x panel ----
    float4* Ws4 = reinterpret_cast<float4*>(Ws);
    for (int i = t; i < 2880; i += 256) {          // 72 rows x 40 float4
        const int row = i / 40, q = i - row * 40;
        const float sc = csm[row * J_U + (q >> 2)];
        const float4 w = Wr4[(size_t)(m0 + row) * 40 + q];
        Ws4[i] = make_float4(w.x * sc, w.y * sc, w.z * sc, w.w * sc);
    }
    for (int i = t; i < 1152; i += 256) {          // 72 rows x 16 float4 (64 b each)
        const int row = i >> 4, col = i & 15;
        const float4 xv = *reinterpret_cast<const float4*>(
            Xt + (size_t)(m0 + row) * B_SZ + bq4 * 64 + col * 4);
        *reinterpret_cast<float4*>(&Xs[row * 64 + col * 4]) = xv;
    }
    __syncthreads();
    // ---- main loop: pure LDS (x b128 conflict-free, w b64 broadcast) ----
    const int bq = t & 15, ng = t >> 4;
    float acc[4][10] = {};
#pragma unroll 4
    for (int m = 0; m < 72; ++m) {
        const float4 cur = *reinterpret_cast<const float4*>(&Xs[m * 64 + bq * 4]);
        const float2* wr = reinterpret_cast<const float2*>(Ws + m * N_DIM + ng * J_U);
        const float xv[4] = {cur.x, cur.y, cur.z, cur.w};
#pragma unroll
        for (int jj = 0; jj < 5; ++jj) {
            const float2 wv = wr[jj];
#pragma unroll
            for (int i = 0; i < 4; ++i) {
                acc[i][2 * jj]     += xv[i] * wv.x;
                acc[i][2 * jj + 1] += xv[i] * wv.y;
            }
        }
    }
    // ---- store split-K partials (plain stores) ----
    float* sp = s_part + (size_t)ch * 40960 + (size_t)(bq4 * 64 + bq * 4) * N_DIM + ng * J_U;
#pragma unroll
    for (int i = 0; i < 4; ++i) {
        float2* p = reinterpret_cast<float2*>(sp + (size_t)i * N_DIM);
#pragma unroll
        for (int jj = 0; jj < 5; ++jj) p[jj] = make_float2(acc[i][2 * jj], acc[i][2 * jj + 1]);
    }
}

// ================= squash: reduce 128 slices (4-way h-split), squash -> dst ========
__global__ __launch_bounds__(640) void k_squash(const float* __restrict__ s_part,
                                                float* __restrict__ dst) {
    __shared__ float red[640];
    __shared__ float sq[160];
    const int b = blockIdx.x, t = threadIdx.x;
    const int n = t % 160, h = t / 160;            // h in 0..3, 32 slices each
    float s = 0.f;
    const float* p = s_part + (size_t)h * 32 * 40960 + (size_t)b * N_DIM + n;
#pragma unroll 8
    for (int sl = 0; sl < 32; ++sl) s += p[(size_t)sl * 40960];
    red[t] = s;
    __syncthreads();
    if (t < 160) {
        s = red[t] + red[t + 160] + red[t + 320] + red[t + 480] + 1e-5f;  // +1e-5 BEFORE mags
        sq[t] = s * s;
        red[t] = s;
    }
    __syncthreads();
    if (t < 160) {
        const int j0 = t & ~15;
        float mag = 0.f;
#pragma unroll
        for (int d = 0; d < 16; ++d) mag += sq[j0 + d];
        dst[(size_t)b * N_DIM + t] = red[t] * (sqrtf(mag) / (1.f + mag));
    }
}

// ================= gemm2: 144 m-tiles(64) x 4 b-quarters(64 b) = 576 blocks =========
// XCD swizzle: vb = (bid%8)*72 + bid/8 (bijective, 576 = 8x72); mt-siblings share
// the XCD L2 for the Wr fold panel and v.
__global__ __launch_bounds__(256) void k_gemm2(const float* __restrict__ x,
                                               const float* __restrict__ v,
                                               const float* __restrict__ Wr,
                                               float* __restrict__ agg_part) {
    __shared__ alignas(16) float VG[64 * 164];   // v-panel [64][160] then G-tile [64][164]
    __shared__ float agg[640];                   // 64 c x 10 j
    const int vb = (blockIdx.x % 8) * 72 + (blockIdx.x / 8);    // XCD-aware remap
    const int mt = vb >> 2, bq = vb & 3;
    const int m0 = mt * 64, b0 = bq * 64;
    const int t = threadIdx.x;
    const int tm = t & 15, ng = t >> 4;

    // stage v quarter (packed [64][160])
    float4* Vs4 = reinterpret_cast<float4*>(VG);
    const float4* v4 = reinterpret_cast<const float4*>(v);
    for (int i = t; i < 2560; i += 256) Vs4[i] = v4[(size_t)bq * 2560 + i];
    for (int i = t; i < 640; i += 256) agg[i] = 0.f;
    __syncthreads();

    // main loop over 64 b: x coalesced (256B/wave-instr), v broadcast from LDS
    float acc[4][10] = {};
    const float* xb = x + (size_t)b0 * M_DIM + m0 + tm * 4;
    const float2* Vs2 = reinterpret_cast<const float2*>(VG);
    float4 pf[4];
#pragma unroll
    for (int i = 0; i < 4; ++i) pf[i] = *reinterpret_cast<const float4*>(xb + (size_t)i * M_DIM);
#pragma unroll 4
    for (int b = 0; b < 64; ++b) {
        const int bf = (b + 4 < 64) ? b + 4 : 63;            // clamped prefetch
        const float4 nxt = *reinterpret_cast<const float4*>(xb + (size_t)bf * M_DIM);
        const float4 cur = pf[0];
        pf[0] = pf[1]; pf[1] = pf[2]; pf[2] = pf[3]; pf[3] = nxt;
        const float2* vv = Vs2 + b * 80 + ng * 5;
        const float xv[4] = {cur.x, cur.y, cur.z, cur.w};
#pragma unroll
        for (int jj = 0; jj < 5; ++jj) {
            const float2 w = vv[jj];
#pragma unroll
            for (int i = 0; i < 4; ++i) {
                acc[i][2 * jj]     += xv[i] * w.x;
                acc[i][2 * jj + 1] += xv[i] * w.y;
            }
        }
    }
    __syncthreads();   // all waves done reading v-panel; reuse VG for G-tile
    // scatter acc -> G-tile (row stride 164 floats = 656 B, 16B-aligned rows)
#pragma unroll
    for (int i = 0; i < 4; ++i)
#pragma unroll
        for (int q = 0; q < 10; ++q)
            VG[(tm * 4 + i) * 164 + ng * 10 + q] = acc[i][q];
    __syncthreads();
    // coalesced fold: 64 rows x 40 float4 of Wr ⊙ G, one j per float4
    const float4* Wr4 = reinterpret_cast<const float4*>(Wr);
    for (int idx = t; idx < 2560; idx += 256) {
        const int row = idx / 40, q = idx - row * 40;
        const float4 w = Wr4[(size_t)(m0 + row) * 40 + q];
        const float4 g = *reinterpret_cast<const float4*>(&VG[row * 164 + q * 4]);
        atomicAdd(&agg[row * J_U + (q >> 2)], w.x * g.x + w.y * g.y + w.z * g.z + w.w * g.w);
    }
    __syncthreads();
    const int k = m0 / C_IN, c0 = m0 - k * C_IN;   // 64-tile never crosses a k-slice
    for (int i = t; i < 640; i += 256)
        agg_part[(size_t)(bq * 8 + k) * 11520 + c0 * J_U + i] = agg[i];
}

extern "C" void kernel_launch(void* const* d_in, const int* in_sizes, int n_in,
                              void* d_out, int out_size, void* d_ws, size_t ws_size,
                              hipStream_t stream) {
    const float* x = (const float*)d_in[0];   // (256, 8, 1152) fp32
    const float* W = (const float*)d_in[1];   // (1, 1152, 10, 16, 8) fp32
    float* out = (float*)d_out;               // (256, 10, 16, 1) fp32
    float* ws  = (float*)d_ws;
    float* Xt   = ws + OFF_XT;
    float* Wr   = ws + OFF_WR;
    float* sp   = ws + OFF_SP;
    float* v    = ws + OFF_V;
    float* bij0 = ws + OFF_B0;
    float* bij1 = ws + OFF_B1;
    float* agg  = ws + OFF_AG;
    const float4* Wr4 = (const float4*)Wr;

    k_prep<<<2016, 256, 0, stream>>>(x, W, ws);

    for (int it = 0; it < 4; ++it) {
        const float* bo = (it & 1) ? bij1 : bij0;
        float*       bn = (it & 1) ? bij0 : bij1;
        k_gemm1<<<512, 256, 0, stream>>>(Xt, Wr4, bo, bn, agg, sp, it == 0 ? 1 : 0);
        k_squash<<<256, 640, 0, stream>>>(sp, (it < 3) ? v : out);
        if (it < 3)   // last iteration's agreement is never used
            k_gemm2<<<576, 256, 0, stream>>>(x, v, Wr, agg);
    }
}